// Round 6
// baseline (793.393 us; speedup 1.0000x reference)
//
#include <hip/hip_runtime.h>
#include <math.h>

#define N_NODES 100000
#define N_EDGES 1600000
#define ET (N_EDGES + N_NODES)
#define F_IN 500
#define D1 128
#define HEADS 8
#define HID 16
#define NCLS 10
#define MAXDEG 64
#define NB 391                        // ceil(N/256) dst-buckets of 256 nodes
#define NSUB 8                        // per-XCD sub-bins (XCC_ID 0..7 measured on MI355X)
#define CAPS 1024                     // capacity per (bucket, xcd) sub-bin (mean 544, +20 sigma)
#define CPAD 16                       // one counter per 64B line

using frag = __attribute__((ext_vector_type(8))) short;   // 8 bf16 (4 VGPR)
using f4   = __attribute__((ext_vector_type(4))) float;   // mfma C/D

__device__ __forceinline__ unsigned short f2bf(float x) {
    unsigned u = __float_as_uint(x);
    unsigned r = u + 0x7fff + ((u >> 16) & 1);
    return (unsigned short)(r >> 16);
}
__device__ __forceinline__ unsigned short f2bf_tr(float x) {   // truncate (lo term)
    return (unsigned short)(__float_as_uint(x) >> 16);
}
__device__ __forceinline__ float bf2f(unsigned short b) {
    return __uint_as_float(((unsigned)b) << 16);
}
__device__ __forceinline__ float bflo(unsigned u) { return __uint_as_float(u << 16); }
__device__ __forceinline__ float bfhi(unsigned u) { return __uint_as_float(u & 0xffff0000u); }
__device__ __forceinline__ float lrelu(float e) { return (e > 0.f) ? e : 0.2f * e; }

// ---------------- pass A: bin edges by (dst>>8, XCC_ID) ---------------------
__global__ __launch_bounds__(256) void k_bin(const int* __restrict__ eidx,
                                             int* __restrict__ bincnt,
                                             int* __restrict__ bin) {
    unsigned xcc;
    asm("s_getreg_b32 %0, hwreg(HW_REG_XCC_ID)" : "=s"(xcc));
    int base = blockIdx.x * 1024 + threadIdx.x;
#pragma unroll
    for (int k = 0; k < 4; k++) {                 // 4 independent chains
        int i = base + k * 256;
        if (i < ET) {
            int s, d;
            if (i < N_EDGES) { s = eidx[i]; d = eidx[N_EDGES + i]; }
            else             { s = i - N_EDGES; d = s; }   // self loop
            int sb = (d >> 8) * NSUB + (int)xcc;
            int pos = atomicAdd(&bincnt[sb * CPAD], 1);
            if (pos < CAPS) bin[(size_t)sb * CAPS + pos] = (s << 8) | (d & 255);
        }
    }
}

// ---------------- pass B: per-bucket LDS scatter -> coalesced slots ---------
__global__ __launch_bounds__(256) void k_build(const int* __restrict__ bincnt,
                                               const int* __restrict__ bin,
                                               int* __restrict__ cnt,
                                               int* __restrict__ slots) {
    __shared__ int lcnt[256];
    __shared__ int lsl[256 * MAXDEG];             // 64 KB
    const int b   = blockIdx.x;
    const int tid = threadIdx.x;
    lcnt[tid] = 0;
    __syncthreads();
    for (int sub = 0; sub < NSUB; sub++) {
        int sb = b * NSUB + sub;
        int len = min(bincnt[sb * CPAD], CAPS);
        const int* bp = bin + (size_t)sb * CAPS;
        for (int i = tid; i < len; i += 256) {
            int v = bp[i];
            int doff = v & 255;
            int j = atomicAdd(&lcnt[doff], 1);    // LDS atomic: cheap, local
            if (j < MAXDEG) lsl[doff * MAXDEG + j] = v >> 8;
        }
    }
    __syncthreads();
    int node0 = b * 256;
    int nloc = min(256, N_NODES - node0);
    if (tid < nloc) cnt[node0 + tid] = min(lcnt[tid], MAXDEG);
    int total4 = (nloc * MAXDEG) >> 2;
    int4* dst4 = (int4*)(slots + (size_t)node0 * MAXDEG);
    const int4* src4 = (const int4*)lsl;
    for (int i = tid; i < total4; i += 256) dst4[i] = src4[i];   // coalesced
}

// ---------------- W -> split-bf16 B-fragment pack ---------------------------
template<int K, int KP>
__global__ __launch_bounds__(256) void k_pack(const float* __restrict__ W,
                                              short* __restrict__ bhi,
                                              short* __restrict__ blo) {
    int t = blockIdx.x * 256 + threadIdx.x;
    if (t >= KP * 128) return;
    int n = t & 127, k = t >> 7;
    float w = (k < K) ? W[k * 128 + n] : 0.f;
    unsigned short h = f2bf(w);
    unsigned short l = f2bf(w - bf2f(h));
    int kt = k >> 5, kq = (k >> 3) & 3, j = k & 7, nt = n >> 4;
    int lane = kq * 16 + (n & 15);
    int idx = ((kt * 8 + nt) * 64 + lane) * 8 + j;
    bhi[idx] = (short)h;
    blo[idx] = (short)l;
}

// ---------------- split-bf16 MFMA GEMM -> packed-bf16 output ----------------
// DMA staging: global_load_lds (width 16) moves raw f32 A HBM->LDS with no
// VGPR round-trip (reg-staged variants were pinned at ~120us, all pipes idle).
// LDS dest must be linear (m104), so the bank-conflict fix is a pre-swizzled
// GLOBAL source granule (g ^ (row&7)) + same XOR on the read side (rule #21).
// OOB handled by address CLAMP (finite garbage * zero-padded B = 0; rows >= n
// never stored) -- exec-masking would leave NaN-able LDS garbage.
template<int K, int NSTEP>
__global__ __launch_bounds__(256, 3) void k_mfma_gemm(const float* __restrict__ A,
                                                      const short* __restrict__ Bhi,
                                                      const short* __restrict__ Blo,
                                                      unsigned* __restrict__ hb, int n) {
    __shared__ float Af[2][128 * 32];             // 2 x 16 KB, [row][32k] f32, swizzled granules
    const int tid  = threadIdx.x;
    const int lane = tid & 63;
    const int w    = tid >> 6;
    const int wm   = w >> 1, wn = w & 1;
    const int r0   = blockIdx.x * 128;
    const size_t lastf = (size_t)n * K - 4;       // clamp target (16B-aligned-safe)

    auto issue = [&](int s, int p) {
        const int k0 = s * 32;
#pragma unroll
        for (int q = 0; q < 4; q++) {
            int gi  = (w * 4 + q) * 64 + lane;    // granule id: 128 rows x 8 granules
            int row = gi >> 3, g = gi & 7;
            int gsw = g ^ (row & 7);              // pre-swizzled source granule
            size_t fidx = (size_t)(r0 + row) * K + k0 + gsw * 4;
            if (fidx > lastf) fidx = lastf;       // finite clamp, never faults
            const float* gp = A + fidx;
            const float* lp = &Af[p][(w * 4 + q) * 256];   // wave-uniform base; HW adds lane*16B
            __builtin_amdgcn_global_load_lds(
                (const __attribute__((address_space(1))) void*)gp,
                (__attribute__((address_space(3))) void*)lp, 16, 0, 0);
        }
    };

    f4 acc[4][4];
#pragma unroll
    for (int a = 0; a < 4; a++)
#pragma unroll
        for (int b = 0; b < 4; b++) acc[a][b] = f4{0.f, 0.f, 0.f, 0.f};

    issue(0, 0);
    int p = 0;
    for (int s = 0; s < NSTEP; s++) {
        __syncthreads();                          // vmcnt drain completes buf p DMA
        if (s + 1 < NSTEP) issue(s + 1, p ^ 1);   // next tile overlaps compute

        frag ahi[4], alo[4];
        const int g0 = (lane >> 4) * 2;           // first wanted granule (8 k-values)
#pragma unroll
        for (int mt = 0; mt < 4; mt++) {
            int row = wm * 64 + mt * 16 + (lane & 15);
            int rb = row * 32, rs = row & 7;
            float4 fa = *(const float4*)(&Af[p][rb + ((g0 ^ rs) << 2)]);
            float4 fb = *(const float4*)(&Af[p][rb + (((g0 + 1) ^ rs) << 2)]);
            float f[8] = {fa.x, fa.y, fa.z, fa.w, fb.x, fb.y, fb.z, fb.w};
            frag h, l;
#pragma unroll
            for (int j = 0; j < 8; j++) {
                unsigned short hh = f2bf(f[j]);
                h[j] = (short)hh;
                l[j] = (short)f2bf_tr(f[j] - bf2f(hh));
            }
            ahi[mt] = h;
            alo[mt] = l;
        }
#pragma unroll
        for (int nn = 0; nn < 4; nn++) {
            int nt = wn * 4 + nn;
            frag bh = *(const frag*)(Bhi + (((size_t)s * 8 + nt) * 64 + lane) * 8);
            frag bl = *(const frag*)(Blo + (((size_t)s * 8 + nt) * 64 + lane) * 8);
#pragma unroll
            for (int mt = 0; mt < 4; mt++) {
                acc[mt][nn] = __builtin_amdgcn_mfma_f32_16x16x32_bf16(ahi[mt], bh, acc[mt][nn], 0, 0, 0);
                acc[mt][nn] = __builtin_amdgcn_mfma_f32_16x16x32_bf16(ahi[mt], bl, acc[mt][nn], 0, 0, 0);
                acc[mt][nn] = __builtin_amdgcn_mfma_f32_16x16x32_bf16(alo[mt], bh, acc[mt][nn], 0, 0, 0);
            }
        }
        p ^= 1;
    }

#pragma unroll
    for (int mt = 0; mt < 4; mt++) {
        int rowb = r0 + wm * 64 + mt * 16 + (lane >> 4) * 4;
#pragma unroll
        for (int nn = 0; nn < 4; nn++) {
#pragma unroll
            for (int i = 0; i < 4; i++) {
                float v  = acc[mt][nn][i];
                float v2 = __shfl_xor(v, 1);
                int row = rowb + i;
                if (!(lane & 1) && row < n) {
                    unsigned pk = (unsigned)f2bf(v) | ((unsigned)f2bf(v2) << 16);
                    hb[(size_t)row * 64 + wn * 32 + nn * 8 + ((lane & 15) >> 1)] = pk;
                }
            }
        }
    }
}

// ---------------- attention logits from packed bf16 h -----------------------
__global__ __launch_bounds__(256) void k_attn_bf(const unsigned* __restrict__ hb,
                                                 const float* __restrict__ a_src,
                                                 const float* __restrict__ a_dst,
                                                 float* __restrict__ als,
                                                 float* __restrict__ ald, int n) {
    int t = blockIdx.x * blockDim.x + threadIdx.x;   // t = node*8 + head
    if (t >= n * 8) return;
    int hd = t & 7;
    const unsigned* hp = hb + (size_t)(t >> 3) * 64 + hd * 8;
    uint4 ua = *(const uint4*)hp;
    uint4 ub = *(const uint4*)(hp + 4);
    unsigned uu[8] = {ua.x, ua.y, ua.z, ua.w, ub.x, ub.y, ub.z, ub.w};
    float s1 = 0.f, s2 = 0.f;
#pragma unroll
    for (int j = 0; j < 8; j++) {
        unsigned u = uu[j];
        float v0 = bflo(u), v1 = bfhi(u);
        s1 += v0 * a_src[hd * 16 + 2 * j] + v1 * a_src[hd * 16 + 2 * j + 1];
        s2 += v0 * a_dst[hd * 16 + 2 * j] + v1 * a_dst[hd * 16 + 2 * j + 1];
    }
    als[t] = s1;
    ald[t] = s2;
}

// ---------------- wave-per-dst single-pass softmax aggregation (128 ch) -----
__global__ __launch_bounds__(256) void k_agg128(const unsigned* __restrict__ hb,
                                                const float* __restrict__ als,
                                                const float* __restrict__ ald,
                                                const int* __restrict__ cnt,
                                                const int* __restrict__ slots,
                                                const float* __restrict__ bias,
                                                const float* __restrict__ gamma,
                                                const float* __restrict__ beta,
                                                float* __restrict__ out, int n) {
    int lane = threadIdx.x & 63;
    int node = __builtin_amdgcn_readfirstlane(blockIdx.x * 4 + (threadIdx.x >> 6));
    if (node >= n) return;
    int head = lane >> 3;
    float aldv = ald[node * 8 + head];
    int deg = min(cnt[node], MAXDEG);
    const int* sl = slots + (long)node * MAXDEG;

    float l = 0.f, accx = 0.f, accy = 0.f;
    int j = 0;
    for (; j + 1 < deg; j += 2) {
        int s0 = sl[j], s1 = sl[j + 1];
        unsigned u0 = hb[(size_t)s0 * 64 + lane];
        unsigned u1 = hb[(size_t)s1 * 64 + lane];
        float p0 = __expf(lrelu(als[s0 * 8 + head] + aldv));
        float p1 = __expf(lrelu(als[s1 * 8 + head] + aldv));
        l += p0 + p1;
        accx += p0 * bflo(u0) + p1 * bflo(u1);
        accy += p0 * bfhi(u0) + p1 * bfhi(u1);
    }
    if (j < deg) {
        int s0 = sl[j];
        unsigned u0 = hb[(size_t)s0 * 64 + lane];
        float p0 = __expf(lrelu(als[s0 * 8 + head] + aldv));
        l += p0;
        accx += p0 * bflo(u0);
        accy += p0 * bfhi(u0);
    }
    float inv = 1.f / fmaxf(l, 1e-16f);
    const float bnr = rsqrtf(1.0f + 1e-5f);
    int c0 = 2 * lane;
    float v0 = accx * inv + bias[c0];
    v0 = (v0 > 0.f) ? v0 : expm1f(v0);
    v0 = v0 * (gamma[c0] * bnr) + beta[c0];
    float v1 = accy * inv + bias[c0 + 1];
    v1 = (v1 > 0.f) ? v1 : expm1f(v1);
    v1 = v1 * (gamma[c0 + 1] * bnr) + beta[c0 + 1];
    out[(long)node * 128 + c0]     = v0;
    out[(long)node * 128 + c0 + 1] = v1;
}

// ---------------- layer-3 GEMM + attn logits (fused) ------------------------
__global__ __launch_bounds__(256) void k_gemm_w3(const float* __restrict__ A,
                                                 const float* __restrict__ W,
                                                 const float* __restrict__ a_src,
                                                 const float* __restrict__ a_dst,
                                                 float* __restrict__ out,
                                                 float* __restrict__ als,
                                                 float* __restrict__ ald, int n) {
    __shared__ float w[D1 * NCLS];
    for (int idx = threadIdx.x; idx < D1 * NCLS; idx += 256) w[idx] = W[idx];
    __syncthreads();
    int node = blockIdx.x * 256 + threadIdx.x;
    if (node >= n) return;
    const float* ar = A + (long)node * D1;
    float acc[NCLS];
#pragma unroll
    for (int cc = 0; cc < NCLS; cc++) acc[cc] = 0.f;
    for (int k = 0; k < D1; k++) {
        float av = ar[k];
#pragma unroll
        for (int cc = 0; cc < NCLS; cc++) acc[cc] = fmaf(av, w[k * NCLS + cc], acc[cc]);
    }
    float s1 = 0.f, s2 = 0.f;
#pragma unroll
    for (int cc = 0; cc < NCLS; cc++) {
        out[(long)node * NCLS + cc] = acc[cc];
        s1 += acc[cc] * a_src[cc];
        s2 += acc[cc] * a_dst[cc];
    }
    als[node] = s1;
    ald[node] = s2;
}

// ---------------- layer-3 aggregation + log_softmax (single-pass) -----------
__global__ __launch_bounds__(256) void k_agg3(const float* __restrict__ h3,
                                              const float* __restrict__ als,
                                              const float* __restrict__ ald,
                                              const int* __restrict__ cnt,
                                              const int* __restrict__ slots,
                                              const float* __restrict__ b3,
                                              float* __restrict__ out, int n) {
    int lane = threadIdx.x & 63;
    int node = __builtin_amdgcn_readfirstlane(blockIdx.x * 4 + (threadIdx.x >> 6));
    if (node >= n) return;
    int g = lane >> 4, r = lane & 15;
    float aldv = ald[node];
    int deg = min(cnt[node], MAXDEG);
    const int* sl = slots + (long)node * MAXDEG;

    float l = 0.f, acc = 0.f;
    for (int j = g; j < deg; j += 4) {
        int s = sl[j];
        float p = __expf(lrelu(als[s] + aldv));
        l += p;
        acc += p * ((r < NCLS) ? h3[(long)s * NCLS + r] : 0.f);
    }
    l   += __shfl_xor(l, 16);   l   += __shfl_xor(l, 32);
    acc += __shfl_xor(acc, 16); acc += __shfl_xor(acc, 32);

    float z = acc / fmaxf(l, 1e-16f) + ((r < NCLS) ? b3[r] : 0.f);
    float zm = (r < NCLS) ? z : -INFINITY;
#pragma unroll
    for (int off = 8; off > 0; off >>= 1) zm = fmaxf(zm, __shfl_xor(zm, off));
    float pe = (r < NCLS) ? __expf(z - zm) : 0.f;
#pragma unroll
    for (int off = 8; off > 0; off >>= 1) pe += __shfl_xor(pe, off);
    if (g == 0 && r < NCLS) out[(long)node * NCLS + r] = z - zm - logf(pe);
}

extern "C" void kernel_launch(void* const* d_in, const int* in_sizes, int n_in,
                              void* d_out, int out_size, void* d_ws, size_t ws_size,
                              hipStream_t stream) {
    const float* x   = (const float*)d_in[0];
    const int*   eix = (const int*)  d_in[1];
    const float* W1  = (const float*)d_in[2];
    const float* a1s = (const float*)d_in[3];
    const float* a1d = (const float*)d_in[4];
    const float* b1  = (const float*)d_in[5];
    const float* g1  = (const float*)d_in[6];
    const float* be1 = (const float*)d_in[7];
    const float* W2  = (const float*)d_in[8];
    const float* a2s = (const float*)d_in[9];
    const float* a2d = (const float*)d_in[10];
    const float* b2  = (const float*)d_in[11];
    const float* g2  = (const float*)d_in[12];
    const float* be2 = (const float*)d_in[13];
    const float* W3  = (const float*)d_in[14];
    const float* a3s = (const float*)d_in[15];
    const float* a3d = (const float*)d_in[16];
    const float* b3  = (const float*)d_in[17];
    float* out = (float*)d_out;

    // workspace carve
    unsigned* hb  = (unsigned*)d_ws;                     // N*64 packed bf16 pairs
    float* feat   = (float*)(hb + (size_t)N_NODES * 64); // N*128 f32
    float* h3     = feat + (size_t)N_NODES * 128;        // N*16 f32 (10 used)
    float* als    = h3   + (size_t)N_NODES * 16;         // N*8
    float* ald    = als  + (size_t)N_NODES * HEADS;      // N*8
    int*   cnt    = (int*)(ald + (size_t)N_NODES * HEADS);  // N ints (compact)
    int*   slots  = cnt + (size_t)N_NODES;               // N*64
    short* b1hi   = (short*)(slots + (size_t)N_NODES * MAXDEG);
    short* b1lo   = b1hi + 512 * 128;
    short* b2hi   = b1lo + 512 * 128;
    short* b2lo   = b2hi + 128 * 128;

    // binning temps aliased onto feat (dead until first k_agg128)
    int* bincnt = (int*)feat;                            // NB*NSUB line-padded counters
    int* bin    = bincnt + (size_t)NB * NSUB * CPAD;     // NB*NSUB*CAPS packed edges

    hipMemsetAsync(bincnt, 0, (size_t)NB * NSUB * CPAD * sizeof(int), stream);
    k_bin<<<(ET + 1023) / 1024, 256, 0, stream>>>(eix, bincnt, bin);
    k_build<<<NB, 256, 0, stream>>>(bincnt, bin, cnt, slots);
    k_pack<F_IN, 512><<<(512 * 128 + 255) / 256, 256, 0, stream>>>(W1, b1hi, b1lo);
    k_pack<D1, 128><<<(128 * 128 + 255) / 256, 256, 0, stream>>>(W2, b2hi, b2lo);

    const int gemm_grid = (N_NODES + 127) / 128;

    // ---- layer 1: 500 -> 8x16 ----
    k_mfma_gemm<F_IN, 16><<<gemm_grid, 256, 0, stream>>>(x, b1hi, b1lo, hb, N_NODES);
    k_attn_bf<<<(N_NODES * 8 + 255) / 256, 256, 0, stream>>>(hb, a1s, a1d, als, ald, N_NODES);
    k_agg128<<<(N_NODES + 3) / 4, 256, 0, stream>>>(hb, als, ald, cnt, slots, b1, g1, be1, feat, N_NODES);

    // ---- layer 2: 128 -> 8x16 ----
    k_mfma_gemm<D1, 4><<<gemm_grid, 256, 0, stream>>>(feat, b2hi, b2lo, hb, N_NODES);
    k_attn_bf<<<(N_NODES * 8 + 255) / 256, 256, 0, stream>>>(hb, a2s, a2d, als, ald, N_NODES);
    k_agg128<<<(N_NODES + 3) / 4, 256, 0, stream>>>(hb, als, ald, cnt, slots, b2, g2, be2, feat, N_NODES);

    // ---- layer 3: 128 -> 10 (1 head) + log_softmax ----
    k_gemm_w3<<<(N_NODES + 255) / 256, 256, 0, stream>>>(feat, W3, a3s, a3d, h3, als, ald, N_NODES);
    k_agg3<<<(N_NODES + 3) / 4, 256, 0, stream>>>(h3, als, ald, cnt, slots, b3, out, N_NODES);
}

// Round 8
// 745.847 us; speedup vs baseline: 1.0637x; 1.0637x over previous
//
#include <hip/hip_runtime.h>
#include <math.h>

#define N_NODES 100000
#define N_EDGES 1600000
#define ET (N_EDGES + N_NODES)
#define F_IN 500
#define D1 128
#define HEADS 8
#define HID 16
#define NCLS 10
#define MAXDEG 64
#define NB 391                        // ceil(N/256) dst-buckets of 256 nodes
#define NSUB 8                        // per-XCD sub-bins (XCC_ID 0..7 measured on MI355X)
#define CAPS 1024                     // capacity per (bucket, xcd) sub-bin (mean 544, +20 sigma)
#define CPAD 16                       // one counter per 64B line

using frag = __attribute__((ext_vector_type(8))) short;   // 8 bf16 (4 VGPR)
using f4   = __attribute__((ext_vector_type(4))) float;   // mfma C/D

__device__ __forceinline__ unsigned short f2bf(float x) {
    unsigned u = __float_as_uint(x);
    unsigned r = u + 0x7fff + ((u >> 16) & 1);
    return (unsigned short)(r >> 16);
}
__device__ __forceinline__ unsigned short f2bf_tr(float x) {   // truncate (lo term)
    return (unsigned short)(__float_as_uint(x) >> 16);
}
__device__ __forceinline__ float bf2f(unsigned short b) {
    return __uint_as_float(((unsigned)b) << 16);
}
__device__ __forceinline__ float bflo(unsigned u) { return __uint_as_float(u << 16); }
__device__ __forceinline__ float bfhi(unsigned u) { return __uint_as_float(u & 0xffff0000u); }
__device__ __forceinline__ float lrelu(float e) { return (e > 0.f) ? e : 0.2f * e; }

// lgkm-only barrier: drains LDS ops (cross-wave visibility) but leaves
// prefetched global loads in flight across the barrier (no vmcnt drain).
__device__ __forceinline__ void barrier_lgkm() {
    asm volatile("s_waitcnt lgkmcnt(0)" ::: "memory");
    __builtin_amdgcn_s_barrier();
    asm volatile("" ::: "memory");
}

// ---------------- pass A: bin edges by (dst>>8, XCC_ID) ---------------------
__global__ __launch_bounds__(256) void k_bin(const int* __restrict__ eidx,
                                             int* __restrict__ bincnt,
                                             int* __restrict__ bin) {
    unsigned xcc;
    asm("s_getreg_b32 %0, hwreg(HW_REG_XCC_ID)" : "=s"(xcc));
    int base = blockIdx.x * 1024 + threadIdx.x;
#pragma unroll
    for (int k = 0; k < 4; k++) {                 // 4 independent chains
        int i = base + k * 256;
        if (i < ET) {
            int s, d;
            if (i < N_EDGES) { s = eidx[i]; d = eidx[N_EDGES + i]; }
            else             { s = i - N_EDGES; d = s; }   // self loop
            int sb = (d >> 8) * NSUB + (int)xcc;
            int pos = atomicAdd(&bincnt[sb * CPAD], 1);
            if (pos < CAPS) bin[(size_t)sb * CAPS + pos] = (s << 8) | (d & 255);
        }
    }
}

// ---------------- pass B: per-bucket LDS scatter -> coalesced slots ---------
__global__ __launch_bounds__(256) void k_build(const int* __restrict__ bincnt,
                                               const int* __restrict__ bin,
                                               int* __restrict__ cnt,
                                               int* __restrict__ slots) {
    __shared__ int lcnt[256];
    __shared__ int lsl[256 * MAXDEG];             // 64 KB
    const int b   = blockIdx.x;
    const int tid = threadIdx.x;
    lcnt[tid] = 0;
    __syncthreads();
    for (int sub = 0; sub < NSUB; sub++) {
        int sb = b * NSUB + sub;
        int len = min(bincnt[sb * CPAD], CAPS);
        const int* bp = bin + (size_t)sb * CAPS;
        for (int i = tid; i < len; i += 256) {
            int v = bp[i];
            int doff = v & 255;
            int j = atomicAdd(&lcnt[doff], 1);    // LDS atomic: cheap, local
            if (j < MAXDEG) lsl[doff * MAXDEG + j] = v >> 8;
        }
    }
    __syncthreads();
    int node0 = b * 256;
    int nloc = min(256, N_NODES - node0);
    if (tid < nloc) cnt[node0 + tid] = min(lcnt[tid], MAXDEG);
    int total4 = (nloc * MAXDEG) >> 2;
    int4* dst4 = (int4*)(slots + (size_t)node0 * MAXDEG);
    const int4* src4 = (const int4*)lsl;
    for (int i = tid; i < total4; i += 256) dst4[i] = src4[i];   // coalesced
}

// ---------------- W -> split-bf16 B-fragment pack ---------------------------
template<int K, int KP>
__global__ __launch_bounds__(256) void k_pack(const float* __restrict__ W,
                                              short* __restrict__ bhi,
                                              short* __restrict__ blo) {
    int t = blockIdx.x * 256 + threadIdx.x;
    if (t >= KP * 128) return;
    int n = t & 127, k = t >> 7;
    float w = (k < K) ? W[k * 128 + n] : 0.f;
    unsigned short h = f2bf(w);
    unsigned short l = f2bf(w - bf2f(h));
    int kt = k >> 5, kq = (k >> 3) & 3, j = k & 7, nt = n >> 4;
    int lane = kq * 16 + (n & 15);
    int idx = ((kt * 8 + nt) * 64 + lane) * 8 + j;
    bhi[idx] = (short)h;
    blo[idx] = (short)l;
}

// ---------------- split-bf16 MFMA GEMM -> packed-bf16 output ----------------
// Round-5 structure (best measured: 117.9us): 64-row tiles, lgkm-only
// barriers keep the s+1 A-prefetch in flight during step-s compute.
template<int K, int NSTEP>
__global__ __launch_bounds__(256, 3) void k_mfma_gemm(const float* __restrict__ A,
                                                      const short* __restrict__ Bhi,
                                                      const short* __restrict__ Blo,
                                                      unsigned* __restrict__ hb, int n) {
    __shared__ short Ah[64 * 40];
    __shared__ short Al[64 * 40];
    const int tid  = threadIdx.x;
    const int lane = tid & 63;
    const int w    = tid >> 6;
    const int wm   = w >> 1, wn = w & 1;
    const int r0   = blockIdx.x * 64;

    float4 ld[2];
    auto issue_loads = [&](int k0) {
#pragma unroll
        for (int p = 0; p < 2; p++) {
            int c = tid + p * 256;
            int row = r0 + (c >> 3);
            int kk = k0 + ((c & 7) << 2);
            if (row < n && kk < K) ld[p] = *(const float4*)(A + (size_t)row * K + kk);
            else                   ld[p] = float4{0.f, 0.f, 0.f, 0.f};
        }
    };
    auto stage = [&]() {
#pragma unroll
        for (int p = 0; p < 2; p++) {
            int c = tid + p * 256;
            int row = c >> 3;
            int kc = (c & 7) << 2;
            float4 v = ld[p];
            unsigned short h0 = f2bf(v.x), h1 = f2bf(v.y), h2 = f2bf(v.z), h3 = f2bf(v.w);
            unsigned short q0 = f2bf_tr(v.x - bf2f(h0)), q1 = f2bf_tr(v.y - bf2f(h1));
            unsigned short q2 = f2bf_tr(v.z - bf2f(h2)), q3 = f2bf_tr(v.w - bf2f(h3));
            int off = row * 40 + kc;
            *(uint2*)(&Ah[off]) = uint2{(unsigned)h0 | ((unsigned)h1 << 16),
                                        (unsigned)h2 | ((unsigned)h3 << 16)};
            *(uint2*)(&Al[off]) = uint2{(unsigned)q0 | ((unsigned)q1 << 16),
                                        (unsigned)q2 | ((unsigned)q3 << 16)};
        }
    };

    f4 acc[2][4];
#pragma unroll
    for (int a = 0; a < 2; a++)
#pragma unroll
        for (int b = 0; b < 4; b++) acc[a][b] = f4{0.f, 0.f, 0.f, 0.f};

    issue_loads(0);
    for (int s = 0; s < NSTEP; s++) {
        if (s > 0) barrier_lgkm();                // all waves done reading LDS
        stage();                                  // waits only ld's vmcnt
        if (s + 1 < NSTEP) issue_loads((s + 1) * 32);   // stays in flight
        barrier_lgkm();                           // LDS writes visible; no vmcnt drain
        frag ahi[2], alo[2];
        const int kb = (lane >> 4) * 8;
#pragma unroll
        for (int mt = 0; mt < 2; mt++) {
            int row = wm * 32 + mt * 16 + (lane & 15);
            ahi[mt] = *(const frag*)(&Ah[row * 40 + kb]);
            alo[mt] = *(const frag*)(&Al[row * 40 + kb]);
        }
#pragma unroll
        for (int nn = 0; nn < 4; nn++) {
            int nt = wn * 4 + nn;
            frag bh = *(const frag*)(Bhi + (((size_t)s * 8 + nt) * 64 + lane) * 8);
            frag bl = *(const frag*)(Blo + (((size_t)s * 8 + nt) * 64 + lane) * 8);
#pragma unroll
            for (int mt = 0; mt < 2; mt++) {
                acc[mt][nn] = __builtin_amdgcn_mfma_f32_16x16x32_bf16(ahi[mt], bh, acc[mt][nn], 0, 0, 0);
                acc[mt][nn] = __builtin_amdgcn_mfma_f32_16x16x32_bf16(ahi[mt], bl, acc[mt][nn], 0, 0, 0);
                acc[mt][nn] = __builtin_amdgcn_mfma_f32_16x16x32_bf16(alo[mt], bh, acc[mt][nn], 0, 0, 0);
            }
        }
    }

#pragma unroll
    for (int mt = 0; mt < 2; mt++) {
        int rowb = r0 + wm * 32 + mt * 16 + (lane >> 4) * 4;
#pragma unroll
        for (int nn = 0; nn < 4; nn++) {
#pragma unroll
            for (int i = 0; i < 4; i++) {
                float v  = acc[mt][nn][i];
                float v2 = __shfl_xor(v, 1);
                int row = rowb + i;
                if (!(lane & 1) && row < n) {
                    unsigned pk = (unsigned)f2bf(v) | ((unsigned)f2bf(v2) << 16);
                    hb[(size_t)row * 64 + wn * 32 + nn * 8 + ((lane & 15) >> 1)] = pk;
                }
            }
        }
    }
}

// ---------------- attention logits from packed bf16 h -----------------------
__global__ __launch_bounds__(256) void k_attn_bf(const unsigned* __restrict__ hb,
                                                 const float* __restrict__ a_src,
                                                 const float* __restrict__ a_dst,
                                                 float* __restrict__ als,
                                                 float* __restrict__ ald, int n) {
    int t = blockIdx.x * blockDim.x + threadIdx.x;   // t = node*8 + head
    if (t >= n * 8) return;
    int hd = t & 7;
    const unsigned* hp = hb + (size_t)(t >> 3) * 64 + hd * 8;
    uint4 ua = *(const uint4*)hp;
    uint4 ub = *(const uint4*)(hp + 4);
    unsigned uu[8] = {ua.x, ua.y, ua.z, ua.w, ub.x, ub.y, ub.z, ub.w};
    float s1 = 0.f, s2 = 0.f;
#pragma unroll
    for (int j = 0; j < 8; j++) {
        unsigned u = uu[j];
        float v0 = bflo(u), v1 = bfhi(u);
        s1 += v0 * a_src[hd * 16 + 2 * j] + v1 * a_src[hd * 16 + 2 * j + 1];
        s2 += v0 * a_dst[hd * 16 + 2 * j] + v1 * a_dst[hd * 16 + 2 * j + 1];
    }
    als[t] = s1;
    ald[t] = s2;
}

// ---------------- wave-per-dst single-pass softmax aggregation (128 ch) -----
// 4-deep gather batch with DIRECT sl[j] loads (wave-uniform addr = broadcast):
// 4 slot loads in one round-trip, then 8 data loads in the next -> ~2x fewer
// serial memory round-trips per edge than the 2-unroll. No shfl (R7 lesson).
__global__ __launch_bounds__(256) void k_agg128(const unsigned* __restrict__ hb,
                                                const float* __restrict__ als,
                                                const float* __restrict__ ald,
                                                const int* __restrict__ cnt,
                                                const int* __restrict__ slots,
                                                const float* __restrict__ bias,
                                                const float* __restrict__ gamma,
                                                const float* __restrict__ beta,
                                                float* __restrict__ out, int n) {
    int lane = threadIdx.x & 63;
    int node = __builtin_amdgcn_readfirstlane(blockIdx.x * 4 + (threadIdx.x >> 6));
    if (node >= n) return;
    int head = lane >> 3;
    float aldv = ald[node * 8 + head];
    int deg = min(cnt[node], MAXDEG);
    const int* sl = slots + (long)node * MAXDEG;

    float l = 0.f, accx = 0.f, accy = 0.f;
    int j = 0;
    for (; j + 3 < deg; j += 4) {
        int s0 = sl[j], s1 = sl[j + 1], s2 = sl[j + 2], s3 = sl[j + 3];
        unsigned u0 = hb[(size_t)s0 * 64 + lane];
        unsigned u1 = hb[(size_t)s1 * 64 + lane];
        unsigned u2 = hb[(size_t)s2 * 64 + lane];
        unsigned u3 = hb[(size_t)s3 * 64 + lane];
        float e0 = als[s0 * 8 + head], e1 = als[s1 * 8 + head];
        float e2 = als[s2 * 8 + head], e3 = als[s3 * 8 + head];
        float p0 = __expf(lrelu(e0 + aldv)), p1 = __expf(lrelu(e1 + aldv));
        float p2 = __expf(lrelu(e2 + aldv)), p3 = __expf(lrelu(e3 + aldv));
        l    += (p0 + p1) + (p2 + p3);
        accx += (p0 * bflo(u0) + p1 * bflo(u1)) + (p2 * bflo(u2) + p3 * bflo(u3));
        accy += (p0 * bfhi(u0) + p1 * bfhi(u1)) + (p2 * bfhi(u2) + p3 * bfhi(u3));
    }
    for (; j < deg; j++) {
        int s0 = sl[j];
        unsigned u0 = hb[(size_t)s0 * 64 + lane];
        float p0 = __expf(lrelu(als[s0 * 8 + head] + aldv));
        l += p0;
        accx += p0 * bflo(u0);
        accy += p0 * bfhi(u0);
    }
    float inv = 1.f / fmaxf(l, 1e-16f);
    const float bnr = rsqrtf(1.0f + 1e-5f);
    int c0 = 2 * lane;
    float v0 = accx * inv + bias[c0];
    v0 = (v0 > 0.f) ? v0 : expm1f(v0);
    v0 = v0 * (gamma[c0] * bnr) + beta[c0];
    float v1 = accy * inv + bias[c0 + 1];
    v1 = (v1 > 0.f) ? v1 : expm1f(v1);
    v1 = v1 * (gamma[c0 + 1] * bnr) + beta[c0 + 1];
    out[(long)node * 128 + c0]     = v0;
    out[(long)node * 128 + c0 + 1] = v1;
}

// ---------------- layer-3 GEMM + attn logits (fused) ------------------------
__global__ __launch_bounds__(256) void k_gemm_w3(const float* __restrict__ A,
                                                 const float* __restrict__ W,
                                                 const float* __restrict__ a_src,
                                                 const float* __restrict__ a_dst,
                                                 float* __restrict__ out,
                                                 float* __restrict__ als,
                                                 float* __restrict__ ald, int n) {
    __shared__ float w[D1 * NCLS];
    for (int idx = threadIdx.x; idx < D1 * NCLS; idx += 256) w[idx] = W[idx];
    __syncthreads();
    int node = blockIdx.x * 256 + threadIdx.x;
    if (node >= n) return;
    const float* ar = A + (long)node * D1;
    float acc[NCLS];
#pragma unroll
    for (int cc = 0; cc < NCLS; cc++) acc[cc] = 0.f;
    for (int k = 0; k < D1; k++) {
        float av = ar[k];
#pragma unroll
        for (int cc = 0; cc < NCLS; cc++) acc[cc] = fmaf(av, w[k * NCLS + cc], acc[cc]);
    }
    float s1 = 0.f, s2 = 0.f;
#pragma unroll
    for (int cc = 0; cc < NCLS; cc++) {
        out[(long)node * NCLS + cc] = acc[cc];
        s1 += acc[cc] * a_src[cc];
        s2 += acc[cc] * a_dst[cc];
    }
    als[node] = s1;
    ald[node] = s2;
}

// ---------------- layer-3 aggregation + log_softmax (single-pass) -----------
// Each 16-lane group handles j = g, g+4, ...; 2 edges in flight per iteration
// via direct sl[j], sl[j+4] loads (no shfl).
__global__ __launch_bounds__(256) void k_agg3(const float* __restrict__ h3,
                                              const float* __restrict__ als,
                                              const float* __restrict__ ald,
                                              const int* __restrict__ cnt,
                                              const int* __restrict__ slots,
                                              const float* __restrict__ b3,
                                              float* __restrict__ out, int n) {
    int lane = threadIdx.x & 63;
    int node = __builtin_amdgcn_readfirstlane(blockIdx.x * 4 + (threadIdx.x >> 6));
    if (node >= n) return;
    int g = lane >> 4, r = lane & 15;
    float aldv = ald[node];
    int deg = min(cnt[node], MAXDEG);
    const int* sl = slots + (long)node * MAXDEG;

    float l = 0.f, acc = 0.f;
    int j = g;
    for (; j + 4 < deg; j += 8) {
        int sa = sl[j], sb = sl[j + 4];
        float ea = als[sa] + aldv, eb = als[sb] + aldv;
        float ha = (r < NCLS) ? h3[(long)sa * NCLS + r] : 0.f;
        float hbv = (r < NCLS) ? h3[(long)sb * NCLS + r] : 0.f;
        float pa = __expf(lrelu(ea)), pb = __expf(lrelu(eb));
        l += pa + pb;
        acc += pa * ha + pb * hbv;
    }
    for (; j < deg; j += 4) {
        int s = sl[j];
        float p = __expf(lrelu(als[s] + aldv));
        l += p;
        acc += p * ((r < NCLS) ? h3[(long)s * NCLS + r] : 0.f);
    }
    l   += __shfl_xor(l, 16);   l   += __shfl_xor(l, 32);
    acc += __shfl_xor(acc, 16); acc += __shfl_xor(acc, 32);

    float z = acc / fmaxf(l, 1e-16f) + ((r < NCLS) ? b3[r] : 0.f);
    float zm = (r < NCLS) ? z : -INFINITY;
#pragma unroll
    for (int off = 8; off > 0; off >>= 1) zm = fmaxf(zm, __shfl_xor(zm, off));
    float pe = (r < NCLS) ? __expf(z - zm) : 0.f;
#pragma unroll
    for (int off = 8; off > 0; off >>= 1) pe += __shfl_xor(pe, off);
    if (g == 0 && r < NCLS) out[(long)node * NCLS + r] = z - zm - logf(pe);
}

extern "C" void kernel_launch(void* const* d_in, const int* in_sizes, int n_in,
                              void* d_out, int out_size, void* d_ws, size_t ws_size,
                              hipStream_t stream) {
    const float* x   = (const float*)d_in[0];
    const int*   eix = (const int*)  d_in[1];
    const float* W1  = (const float*)d_in[2];
    const float* a1s = (const float*)d_in[3];
    const float* a1d = (const float*)d_in[4];
    const float* b1  = (const float*)d_in[5];
    const float* g1  = (const float*)d_in[6];
    const float* be1 = (const float*)d_in[7];
    const float* W2  = (const float*)d_in[8];
    const float* a2s = (const float*)d_in[9];
    const float* a2d = (const float*)d_in[10];
    const float* b2  = (const float*)d_in[11];
    const float* g2  = (const float*)d_in[12];
    const float* be2 = (const float*)d_in[13];
    const float* W3  = (const float*)d_in[14];
    const float* a3s = (const float*)d_in[15];
    const float* a3d = (const float*)d_in[16];
    const float* b3  = (const float*)d_in[17];
    float* out = (float*)d_out;

    // workspace carve
    unsigned* hb  = (unsigned*)d_ws;                     // N*64 packed bf16 pairs
    float* feat   = (float*)(hb + (size_t)N_NODES * 64); // N*128 f32
    float* h3     = feat + (size_t)N_NODES * 128;        // N*16 f32 (10 used)
    float* als    = h3   + (size_t)N_NODES * 16;         // N*8
    float* ald    = als  + (size_t)N_NODES * HEADS;      // N*8
    int*   cnt    = (int*)(ald + (size_t)N_NODES * HEADS);  // N ints (compact)
    int*   slots  = cnt + (size_t)N_NODES;               // N*64
    short* b1hi   = (short*)(slots + (size_t)N_NODES * MAXDEG);
    short* b1lo   = b1hi + 512 * 128;
    short* b2hi   = b1lo + 512 * 128;
    short* b2lo   = b2hi + 128 * 128;

    // binning temps aliased onto feat (dead until first k_agg128)
    int* bincnt = (int*)feat;                            // NB*NSUB line-padded counters
    int* bin    = bincnt + (size_t)NB * NSUB * CPAD;     // NB*NSUB*CAPS packed edges

    hipMemsetAsync(bincnt, 0, (size_t)NB * NSUB * CPAD * sizeof(int), stream);
    k_bin<<<(ET + 1023) / 1024, 256, 0, stream>>>(eix, bincnt, bin);
    k_build<<<NB, 256, 0, stream>>>(bincnt, bin, cnt, slots);
    k_pack<F_IN, 512><<<(512 * 128 + 255) / 256, 256, 0, stream>>>(W1, b1hi, b1lo);
    k_pack<D1, 128><<<(128 * 128 + 255) / 256, 256, 0, stream>>>(W2, b2hi, b2lo);

    const int gemm_grid = (N_NODES + 63) / 64;

    // ---- layer 1: 500 -> 8x16 ----
    k_mfma_gemm<F_IN, 16><<<gemm_grid, 256, 0, stream>>>(x, b1hi, b1lo, hb, N_NODES);
    k_attn_bf<<<(N_NODES * 8 + 255) / 256, 256, 0, stream>>>(hb, a1s, a1d, als, ald, N_NODES);
    k_agg128<<<(N_NODES + 3) / 4, 256, 0, stream>>>(hb, als, ald, cnt, slots, b1, g1, be1, feat, N_NODES);

    // ---- layer 2: 128 -> 8x16 ----
    k_mfma_gemm<D1, 4><<<gemm_grid, 256, 0, stream>>>(feat, b2hi, b2lo, hb, N_NODES);
    k_attn_bf<<<(N_NODES * 8 + 255) / 256, 256, 0, stream>>>(hb, a2s, a2d, als, ald, N_NODES);
    k_agg128<<<(N_NODES + 3) / 4, 256, 0, stream>>>(hb, als, ald, cnt, slots, b2, g2, be2, feat, N_NODES);

    // ---- layer 3: 128 -> 10 (1 head) + log_softmax ----
    k_gemm_w3<<<(N_NODES + 255) / 256, 256, 0, stream>>>(feat, W3, a3s, a3d, h3, als, ald, N_NODES);
    k_agg3<<<(N_NODES + 3) / 4, 256, 0, stream>>>(h3, als, ald, cnt, slots, b3, out, N_NODES);
}